// Round 11
// baseline (428.201 us; speedup 1.0000x reference)
//
#include <hip/hip_runtime.h>
#include <math.h>

#define BSZ 4
#define DD 48
#define SS (48*48*48)          // 110592 spatial per (b, channel)
#define NV (BSZ*SS)            // 442368 voxels per channel over batch
#define PS 125000              // 50^3 padded volume
#define EPSBN 1e-5f

typedef __attribute__((ext_vector_type(8))) short bf16x8;
typedef __attribute__((ext_vector_type(4))) short s16x4;
typedef __attribute__((ext_vector_type(4))) float f32x4;

__device__ __forceinline__ short f2b(float f){           // fp32 -> bf16 bits (RNE)
  unsigned u = __float_as_uint(f);
  u = (u + 0x7FFFu + ((u>>16)&1u)) >> 16;
  return (short)u;
}
__device__ __forceinline__ float b2f(short s){
  return __uint_as_float(((unsigned)(unsigned short)s)<<16);
}

// ---------------- pad + pairify: x (4,48^3) fp32 -> pairh (4,50^3) uint -----
__global__ __launch_bounds__(256) void pad_pair_kernel(
    const float* __restrict__ src, unsigned* __restrict__ dst)
{
  int idx = blockIdx.x*256 + threadIdx.x;
  if (idx >= BSZ*PS) return;
  int b = idx / PS; int r = idx - b*PS;
  int z = r/2500; int r2 = r - z*2500; int yy = r2/50; int xx = r2 - yy*50;
  const float* sb = src + (size_t)b*SS;
  auto val = [&](int zz,int yv,int xv)->unsigned{
    float v = 0.f;
    if (zz>=1 && zz<=48 && yv>=1 && yv<=48 && xv>=1 && xv<=48)
      v = sb[(size_t)((zz-1)*48 + (yv-1))*48 + (xv-1)];
    return (unsigned)(unsigned short)f2b(v);
  };
  unsigned lo = val(z,yy,xx);
  unsigned hi = (xx<49) ? val(z,yy,xx+1) : 0u;
  dst[idx] = lo | (hi<<16);
}

// ---------------- fused BN+relu+pad+pairify: y -> pairh ---------------------
__global__ __launch_bounds__(256) void bnpad_pair_kernel(
    const float* __restrict__ y, const float* __restrict__ st,
    const float* __restrict__ gamma, const float* __restrict__ beta,
    unsigned* __restrict__ dst)
{
  int idx = blockIdx.x*256 + threadIdx.x;
  if (idx >= BSZ*PS) return;
  float mu  = st[0]*(1.f/(float)NV);
  float var = st[1]*(1.f/(float)NV) - mu*mu;
  float sc  = rsqrtf(var+EPSBN)*gamma[0];
  float sh  = beta[0] - mu*sc;
  int b = idx / PS; int r = idx - b*PS;
  int z = r/2500; int r2 = r - z*2500; int yy = r2/50; int xx = r2 - yy*50;
  const float* yb = y + (size_t)b*SS;
  auto val = [&](int zz,int yv,int xv)->unsigned{
    float v = 0.f;
    if (zz>=1 && zz<=48 && yv>=1 && yv<=48 && xv>=1 && xv<=48){
      float t = yb[(size_t)((zz-1)*48 + (yv-1))*48 + (xv-1)];
      v = fmaxf(fmaf(t, sc, sh), 0.f);
    }
    return (unsigned)(unsigned short)f2b(v);
  };
  unsigned lo = val(z,yy,xx);
  unsigned hi = (xx<49) ? val(z,yy,xx+1) : 0u;
  dst[idx] = lo | (hi<<16);
}

// ---------------- merged weight repack: wbf + wo2 + wc1b --------------------
// [0,55296): conv2 (co,ci,tap)->(tap,co,ci); [55296,58880): offset/mask;
// [58880,59904): conv1.
__global__ void repack_kernel(
    const float* __restrict__ w_c2,
    const float* __restrict__ w_p, const float* __restrict__ b_p,
    const float* __restrict__ w_m, const float* __restrict__ b_m,
    const float* __restrict__ w_c1,
    short* __restrict__ wbf, short* __restrict__ wo2, short* __restrict__ wc1b)
{
  int o = blockIdx.x*256 + threadIdx.x;
  if (o < 27*64*32){
    int ci = o & 31; int co = (o>>5) & 63; int tap = o >> 11;
    wbf[o] = f2b(w_c2[(co*32+ci)*27 + tap]);
  } else if (o < 27*64*32 + 112*32){
    int o2 = o - 27*64*32;
    int k = o2 & 31; int c = o2 >> 5;
    int f = c >> 4, qq = (c >> 2) & 3, r = c & 3;
    int n = 4*f + qq;
    float v = 0.f;
    if (n < 27){
      if (k < 27)       v = (r < 3) ? w_p[(r*27+n)*27 + k] : w_m[n*27 + k];
      else if (k == 27) v = (r < 3) ? b_p[r*27+n]          : b_m[n];
    }
    wo2[o2] = f2b(v);
  } else if (o < 27*64*32 + 112*32 + 32*32){
    int o3 = o - 27*64*32 - 112*32;
    int k = o3 & 31; int c = o3 >> 5;
    wc1b[o3] = f2b(k < 27 ? w_c1[c*27 + k] : 0.f);
  }
}

// ---------------- deformable conv stage: pair-gather, barrier-free p dump ---
template<bool WRITE_P>
__global__ __launch_bounds__(256) void deform3_kernel(
    const unsigned* __restrict__ xpair,   // (4,50^3) bf16-pair table
    const short* __restrict__ wo2,        // [112][32] bf16
    const float* __restrict__ w_dc,
    float* __restrict__ y, float* __restrict__ p_out,
    float* __restrict__ st)               // [2] sum/sumsq of y (atomic)
{
  __shared__ short xt[6*6*18];                         // 2592 B halo (bf16)
  __shared__ __align__(16) float pbuf[WRITE_P ? 4*16*81 : 4];  // per-wave slices
  __shared__ float yred[8];

  int bid = blockIdx.x;
  int bw = bid % 3; int bh = (bid/3)%12; int bd = (bid/36)%12; int b = bid/432;
  int d0 = bd*4, h0 = bh*4, w0 = bw*16;
  int tid = threadIdx.x;
  const unsigned* xp = xpair + (size_t)b*PS;

  for (int e = tid; e < 648; e += 256){
    int z = e/108; int rem = e - z*108; int yy = rem/18; int xx = rem - yy*18;
    xt[e] = (short)(xp[(d0+z)*2500 + (h0+yy)*50 + (w0+xx)] & 0xffffu);
  }
  __syncthreads();

  int lane = tid & 63, wid = tid >> 6;
  int q = lane >> 4, n16 = lane & 15;

  bf16x8 aF[7];
  #pragma unroll
  for (int f=0; f<7; ++f)
    aF[f] = *(const bf16x8*)(wo2 + (f*16 + n16)*32 + q*8);

  int toffs[8];
  #pragma unroll
  for (int j=0;j<8;++j){
    int t = q*8 + j; int tc = t > 26 ? 0 : t;
    int kd = tc/9, rr = tc - kd*9, kh = rr/3, kw = rr - kh*3;
    toffs[j] = kd*108 + kh*18 + kw;
  }

  float wdcv[7], fkd[7], fkh[7], fkw[7];
  #pragma unroll
  for (int f=0; f<7; ++f){
    int n = 4*f + q;
    if (n < 27){
      int kd = n/9, rr = n - kd*9, kh = rr/3, kw = rr - kh*3;
      wdcv[f] = w_dc[n];
      fkd[f] = (float)kd; fkh[f] = (float)kh; fkw[f] = (float)kw;
    } else { wdcv[f]=0.f; fkd[f]=0.f; fkh[f]=0.f; fkw[f]=0.f; }
  }

  const short one_bf = (short)0x3F80;
  const f32x4 zero4 = {0.f,0.f,0.f,0.f};
  float based = (float)(d0 + wid);
  float basew = (float)(w0 + n16);
  float ys = 0.f, yq = 0.f;
  float* pw = pbuf + wid*1296;          // this wave's 16x81 slice

  #pragma unroll 1
  for (int dy=0; dy<4; ++dy){
    int vbase = wid*108 + dy*18 + n16;
    bf16x8 bF;
    #pragma unroll
    for (int j=0;j<8;++j){
      short xv = xt[vbase + toffs[j]];
      bF[j] = (j<3 || q<3) ? xv : one_bf;
    }
    f32x4 acc[7];
    #pragma unroll
    for (int f=0; f<7; ++f)
      acc[f] = __builtin_amdgcn_mfma_f32_16x16x32_bf16(aF[f], bF, zero4, 0,0,0);

    float baseh = (float)(h0 + dy);
    float accv = 0.f;
    #pragma unroll
    for (int f=0; f<7; ++f){
      int n = 4*f + q;
      if (n < 27){
        float od = acc[f][0], oh = acc[f][1], ow = acc[f][2], mr = acc[f][3];
        float mm = __builtin_amdgcn_rcpf(1.f + __expf(-mr));
        float pdv = based + fkd[f] + od;
        float phv = baseh + fkh[f] + oh;
        float pwv = basew + fkw[f] + ow;
        float fd0 = fminf(fmaxf(floorf(pdv),0.f),49.f), fd1 = fminf(fd0+1.f,49.f);
        float pdc = fminf(fmaxf(pdv,0.f),49.f);
        float wd0 = 1.f + fd0 - pdc, wd1 = 1.f - fd1 + pdc;
        float fh0 = fminf(fmaxf(floorf(phv),0.f),49.f), fh1 = fminf(fh0+1.f,49.f);
        float phc = fminf(fmaxf(phv,0.f),49.f);
        float wh0 = 1.f + fh0 - phc, wh1 = 1.f - fh1 + phc;
        float fw0 = fminf(fmaxf(floorf(pwv),0.f),49.f);
        float pwc = fminf(fmaxf(pwv,0.f),49.f);
        float fw1 = fminf(fw0+1.f,49.f);
        float wwa = 1.f + fw0 - pwc, wwb = 1.f - fw1 + pwc;
        int iz0 = (int)fd0*2500, iz1 = (int)fd1*2500;
        int iy0 = (int)fh0*50,   iy1 = (int)fh1*50;
        int ix0 = (int)fw0;
        bool sel = ix0 > 48;
        int ixp = sel ? 48 : ix0;
        unsigned p00 = xp[iz0+iy0+ixp], p01 = xp[iz0+iy1+ixp];
        unsigned p10 = xp[iz1+iy0+ixp], p11 = xp[iz1+iy1+ixp];
        float lo00=b2f((short)p00), hi00=b2f((short)(p00>>16));
        float lo01=b2f((short)p01), hi01=b2f((short)(p01>>16));
        float lo10=b2f((short)p10), hi10=b2f((short)(p10>>16));
        float lo11=b2f((short)p11), hi11=b2f((short)(p11>>16));
        float v000 = sel ? hi00 : lo00, v001 = hi00;
        float v010 = sel ? hi01 : lo01, v011 = hi01;
        float v100 = sel ? hi10 : lo10, v101 = hi10;
        float v110 = sel ? hi11 : lo11, v111 = hi11;
        float sv = wd0*(wh0*(wwa*v000+wwb*v001)+wh1*(wwa*v010+wwb*v011))
                 + wd1*(wh0*(wwa*v100+wwb*v101)+wh1*(wwa*v110+wwb*v111));
        accv += sv*mm*wdcv[f];
        if constexpr (WRITE_P){
          int vb = n16*81;
          pw[vb + n]      = pdc;
          pw[vb + 27 + n] = phc;
          pw[vb + 54 + n] = pwc;
        }
      }
    }
    accv += __shfl_xor(accv, 16);
    accv += __shfl_xor(accv, 32);
    if (q == 0){
      y[(size_t)b*SS + (size_t)((d0+wid)*48 + (h0+dy))*48 + (w0+n16)] = accv;
      ys += accv; yq += accv*accv;
    }

    if constexpr (WRITE_P){
      // per-wave dump: no barrier (intra-wave LDS RAW handled by waitcnt)
      size_t rbase = ((((size_t)b*48 + (d0+wid))*48 + (h0+dy))*48 + w0)*81;
      float* dst = p_out + rbase;
      #pragma unroll
      for (int k=0;k<6;++k){
        int i = lane + (k<<6);
        if (i < 324){
          f32x4 v = *(const f32x4*)(pw + i*4);
          *(f32x4*)(dst + i*4) = v;
        }
      }
    }
  }

  // fused y-stats: q==0 lanes (0..15) hold per-voxel partials
  ys += __shfl_xor(ys, 1); ys += __shfl_xor(ys, 2);
  ys += __shfl_xor(ys, 4); ys += __shfl_xor(ys, 8);
  yq += __shfl_xor(yq, 1); yq += __shfl_xor(yq, 2);
  yq += __shfl_xor(yq, 4); yq += __shfl_xor(yq, 8);
  if (lane == 0){ yred[wid] = ys; yred[4+wid] = yq; }
  __syncthreads();
  if (tid == 0) atomicAdd(&st[0], yred[0]+yred[1]+yred[2]+yred[3]);
  if (tid == 1) atomicAdd(&st[1], yred[4]+yred[5]+yred[6]+yred[7]);
}

// ---------------- conv1 via MFMA + fused BN stats ---------------------------
__global__ __launch_bounds__(256) void conv1m_kernel(
    const unsigned* __restrict__ xpair, const short* __restrict__ wc1b,
    short* __restrict__ h1c, float* __restrict__ st)
{
  __shared__ short xt[6*6*18];
  __shared__ float red[4][4][16];      // [wid][q][16 vals]
  int bid = blockIdx.x;
  int bw = bid % 3; int bh = (bid/3)%12; int bd = (bid/36)%12; int b = bid/432;
  int d0 = bd*4, h0 = bh*4, w0 = bw*16;
  int tid = threadIdx.x;
  const unsigned* xp = xpair + (size_t)b*PS;

  for (int e = tid; e < 648; e += 256){
    int z = e/108; int rem = e - z*108; int yy = rem/18; int xx = rem - yy*18;
    xt[e] = (short)(xp[(d0+z)*2500 + (h0+yy)*50 + (w0+xx)] & 0xffffu);
  }
  __syncthreads();

  int lane = tid & 63, wid = tid >> 6;
  int q = lane >> 4, n16 = lane & 15;

  bf16x8 aF0 = *(const bf16x8*)(wc1b + n16*32 + q*8);
  bf16x8 aF1 = *(const bf16x8*)(wc1b + (16+n16)*32 + q*8);

  int toffs[8];
  #pragma unroll
  for (int j=0;j<8;++j){
    int t = q*8 + j; int tc = t > 26 ? 0 : t;
    int kd = tc/9, rr = tc - kd*9, kh = rr/3, kw = rr - kh*3;
    toffs[j] = kd*108 + kh*18 + kw;
  }

  const f32x4 zero4 = {0.f,0.f,0.f,0.f};
  f32x4 s0 = zero4, q0v = zero4, s1 = zero4, q1v = zero4;
  #pragma unroll
  for (int dy=0; dy<4; ++dy){
    int vbase = wid*108 + dy*18 + n16;
    bf16x8 bF;
    #pragma unroll
    for (int j=0;j<8;++j) bF[j] = xt[vbase + toffs[j]];   // A k>=27 is 0
    f32x4 a0 = __builtin_amdgcn_mfma_f32_16x16x32_bf16(aF0, bF, zero4, 0,0,0);
    f32x4 a1 = __builtin_amdgcn_mfma_f32_16x16x32_bf16(aF1, bF, zero4, 0,0,0);
    size_t idx = (size_t)b*SS + (size_t)((d0+wid)*48 + (h0+dy))*48 + (w0+n16);
    s16x4 o0, o1;
    #pragma unroll
    for (int r=0;r<4;++r){ o0[r]=f2b(a0[r]); o1[r]=f2b(a1[r]); }
    *(s16x4*)(h1c + idx*32 + q*4)      = o0;
    *(s16x4*)(h1c + idx*32 + 16 + q*4) = o1;
    #pragma unroll
    for (int r=0;r<4;++r){
      float v0 = b2f(o0[r]); s0[r]+=v0; q0v[r]+=v0*v0;
      float v1 = b2f(o1[r]); s1[r]+=v1; q1v[r]+=v1*v1;
    }
  }
  // reduce over n16 lanes (bits 0..3), q preserved
  #pragma unroll
  for (int m=1; m<16; m<<=1){
    #pragma unroll
    for (int r=0;r<4;++r){
      s0[r]+=__shfl_xor(s0[r],m);  q0v[r]+=__shfl_xor(q0v[r],m);
      s1[r]+=__shfl_xor(s1[r],m);  q1v[r]+=__shfl_xor(q1v[r],m);
    }
  }
  if (n16 == 0){
    #pragma unroll
    for (int r=0;r<4;++r){
      red[wid][q][r]    = s0[r];
      red[wid][q][4+r]  = s1[r];
      red[wid][q][8+r]  = q0v[r];
      red[wid][q][12+r] = q1v[r];
    }
  }
  __syncthreads();
  if (tid < 64){
    int qq = tid >> 4, v = tid & 15;
    float t = red[0][qq][v] + red[1][qq][v] + red[2][qq][v] + red[3][qq][v];
    int r = v & 3;
    int ch = ((v>>2)&1) ? (16 + qq*4 + r) : (qq*4 + r);
    int issq = v >> 3;
    atomicAdd(&st[2*ch + issq], t);
  }
}

// ---------------- conv2 via MFMA, inline BN+relu staging + fused t2 stats ---
__global__ __launch_bounds__(256) void conv2_mfma2(
    const short* __restrict__ h1c, const short* __restrict__ wbf,
    const float* __restrict__ st1, const float* __restrict__ g1,
    const float* __restrict__ be1, short* __restrict__ t2c,
    float* __restrict__ st2)
{
  __shared__ __align__(16) short slab[4*648*8];  // 41472 B
  __shared__ float ssc[32], ssh[32];
  __shared__ float red[4][4][4][8];              // [wid][q][mb][8]
  int tid = threadIdx.x;
  if (tid < 32){
    float mu  = st1[2*tid]  *(1.f/(float)NV);
    float var = st1[2*tid+1]*(1.f/(float)NV) - mu*mu;
    float sc = rsqrtf(var+EPSBN)*g1[tid];
    ssc[tid]=sc; ssh[tid]=be1[tid]-mu*sc;
  }
  __syncthreads();

  int bid0 = blockIdx.x;
  int bid = (bid0 & 7)*216 + (bid0 >> 3);        // bijective XCD swizzle (1728=8*216)
  int bw = bid % 3; int bh = (bid/3)%12; int bd = (bid/36)%12; int b = bid/432;
  int d0 = bd*4, h0 = bh*4, w0 = bw*16;
  const short* hb = h1c + (size_t)b*SS*32;

  for (int e = tid; e < 648; e += 256){
    int z = e/108; int rem = e - z*108; int y = rem/18; int x = rem - y*18;
    int gd = d0-1+z, gh = h0-1+y, gw = w0-1+x;
    bool ok = ((unsigned)gd<48u)&&((unsigned)gh<48u)&&((unsigned)gw<48u);
    if (ok){
      const bf16x8* src = (const bf16x8*)(hb + (size_t)((gd*48+gh)*48+gw)*32);
      #pragma unroll
      for (int g8=0; g8<4; ++g8){
        bf16x8 raw = src[g8];
        bf16x8 outv;
        #pragma unroll
        for (int j=0;j<8;++j){
          float v = fmaxf(fmaf(b2f(raw[j]), ssc[g8*8+j], ssh[g8*8+j]), 0.f);
          outv[j] = f2b(v);
        }
        *(bf16x8*)&slab[(g8*648+e)*8] = outv;
      }
    } else {
      bf16x8 zz = {0,0,0,0,0,0,0,0};
      #pragma unroll
      for (int g8=0; g8<4; ++g8) *(bf16x8*)&slab[(g8*648+e)*8] = zz;
    }
  }
  __syncthreads();

  int lane = tid & 63, wid = tid >> 6;
  int q = lane >> 4, n16 = lane & 15;
  f32x4 zero4 = {0.f,0.f,0.f,0.f};
  f32x4 acc[4][4];
  #pragma unroll
  for (int i=0;i<4;++i)
  #pragma unroll
  for (int j=0;j<4;++j) acc[i][j] = zero4;

  #pragma unroll 1
  for (int tap=0; tap<27; ++tap){
    int kd = tap/9; int kh = (tap/3)%3; int kw = tap%3;
    const short* wp = wbf + (size_t)tap*64*32 + n16*32 + q*8;
    bf16x8 aF[4];
    #pragma unroll
    for (int mb=0; mb<4; ++mb)
      aF[mb] = *(const bf16x8*)(wp + mb*16*32);

    int zz = wid + kd;
    #pragma unroll
    for (int dy=0; dy<4; ++dy){
      int e = (zz*6 + (dy+kh))*18 + (n16+kw);
      bf16x8 bF = *(const bf16x8*)&slab[(q*648 + e)*8];
      #pragma unroll
      for (int mb=0; mb<4; ++mb)
        acc[mb][dy] = __builtin_amdgcn_mfma_f32_16x16x32_bf16(aF[mb], bF, acc[mb][dy], 0,0,0);
    }
  }

  short* tb = t2c + (size_t)b*SS*64;
  f32x4 sacc[4], qacc[4];
  #pragma unroll
  for (int mb=0; mb<4; ++mb){ sacc[mb]=zero4; qacc[mb]=zero4; }
  #pragma unroll
  for (int dy=0; dy<4; ++dy){
    int svox = ((d0+wid)*48 + (h0+dy))*48 + (w0+n16);
    #pragma unroll
    for (int mb=0; mb<4; ++mb){
      s16x4 o4;
      #pragma unroll
      for (int r=0;r<4;++r){
        o4[r] = f2b(acc[mb][dy][r]);
        float v = b2f(o4[r]);
        sacc[mb][r] += v; qacc[mb][r] += v*v;
      }
      *(s16x4*)(tb + (size_t)svox*64 + mb*16 + q*4) = o4;
    }
  }
  // reduce stats over n16 lanes (bits 0..3), q preserved
  #pragma unroll
  for (int m=1; m<16; m<<=1){
    #pragma unroll
    for (int mb=0; mb<4; ++mb){
      #pragma unroll
      for (int r=0;r<4;++r){
        sacc[mb][r]+=__shfl_xor(sacc[mb][r],m);
        qacc[mb][r]+=__shfl_xor(qacc[mb][r],m);
      }
    }
  }
  if (n16 == 0){
    #pragma unroll
    for (int mb=0; mb<4; ++mb){
      #pragma unroll
      for (int r=0;r<4;++r){
        red[wid][q][mb][r]   = sacc[mb][r];
        red[wid][q][mb][4+r] = qacc[mb][r];
      }
    }
  }
  __syncthreads();
  if (tid < 128){
    int qq = (tid>>5)&3, mb = (tid>>3)&3, v = tid&7;
    float t = red[0][qq][mb][v] + red[1][qq][mb][v] + red[2][qq][mb][v] + red[3][qq][mb][v];
    int r = v & 3, issq = v >> 2;
    int ch = mb*16 + qq*4 + r;
    atomicAdd(&st2[2*ch + issq], t);
  }
}

// ---------------- BN + relu + maxpool + spatial-sum, channel-last -----------
__global__ __launch_bounds__(128) void pool64c_kernel(
    const short* __restrict__ t2c, const float* __restrict__ sums,
    const float* __restrict__ gamma, const float* __restrict__ beta,
    float* __restrict__ pooled)
{
  __shared__ float ssc[64], ssh[64];
  int tid = threadIdx.x;
  if (tid < 64){
    float mu  = sums[2*tid]  *(1.f/(float)NV);
    float var = sums[2*tid+1]*(1.f/(float)NV) - mu*mu;
    float sc = rsqrtf(var+EPSBN)*gamma[tid];
    ssc[tid]=sc; ssh[tid]=beta[tid]-mu*sc;
  }
  __syncthreads();
  int b = blockIdx.z, pd = blockIdx.y, ph = blockIdx.x;
  int c8 = tid & 7, pw = tid >> 3;
  const short* tb = t2c + (size_t)b*SS*64;
  f32x4 mxa = {-1e30f,-1e30f,-1e30f,-1e30f}, mxb = mxa;
  float sc0=ssc[c8*8+0], sc1=ssc[c8*8+1], sc2=ssc[c8*8+2], sc3=ssc[c8*8+3];
  float sc4=ssc[c8*8+4], sc5=ssc[c8*8+5], sc6=ssc[c8*8+6], sc7=ssc[c8*8+7];
  float sh0=ssh[c8*8+0], sh1=ssh[c8*8+1], sh2=ssh[c8*8+2], sh3=ssh[c8*8+3];
  float sh4=ssh[c8*8+4], sh5=ssh[c8*8+5], sh6=ssh[c8*8+6], sh7=ssh[c8*8+7];
  #pragma unroll
  for (int kd=0;kd<3;++kd)
  #pragma unroll 1
  for (int kh=0;kh<3;++kh)
  #pragma unroll
  for (int kw=0;kw<3;++kw){
    int vox = ((pd*3+kd)*48 + (ph*3+kh))*48 + (pw*3+kw);
    bf16x8 v8 = *(const bf16x8*)(tb + (size_t)vox*64 + c8*8);
    float v;
    v = fmaxf(fmaf(b2f(v8[0]), sc0, sh0), 0.f); mxa[0] = fmaxf(mxa[0], v);
    v = fmaxf(fmaf(b2f(v8[1]), sc1, sh1), 0.f); mxa[1] = fmaxf(mxa[1], v);
    v = fmaxf(fmaf(b2f(v8[2]), sc2, sh2), 0.f); mxa[2] = fmaxf(mxa[2], v);
    v = fmaxf(fmaf(b2f(v8[3]), sc3, sh3), 0.f); mxa[3] = fmaxf(mxa[3], v);
    v = fmaxf(fmaf(b2f(v8[4]), sc4, sh4), 0.f); mxb[0] = fmaxf(mxb[0], v);
    v = fmaxf(fmaf(b2f(v8[5]), sc5, sh5), 0.f); mxb[1] = fmaxf(mxb[1], v);
    v = fmaxf(fmaf(b2f(v8[6]), sc6, sh6), 0.f); mxb[2] = fmaxf(mxb[2], v);
    v = fmaxf(fmaf(b2f(v8[7]), sc7, sh7), 0.f); mxb[3] = fmaxf(mxb[3], v);
  }
  __shared__ float r[128][8];
  r[tid][0]=mxa[0]; r[tid][1]=mxa[1]; r[tid][2]=mxa[2]; r[tid][3]=mxa[3];
  r[tid][4]=mxb[0]; r[tid][5]=mxb[1]; r[tid][6]=mxb[2]; r[tid][7]=mxb[3];
  __syncthreads();
  for (int o=64;o>=8;o>>=1){
    if (tid<o){
      #pragma unroll
      for (int j=0;j<8;++j) r[tid][j]+=r[tid+o][j];
    }
    __syncthreads();
  }
  if (tid<8){
    #pragma unroll
    for (int j=0;j<8;++j) atomicAdd(&pooled[b*64 + tid*8 + j], r[tid][j]);
  }
}

// ---------------- FC head ----------------
__global__ void fc_kernel(const float* __restrict__ pooled,
                          const float* __restrict__ w_fc, const float* __restrict__ b_fc,
                          float* __restrict__ logits)
{
  int t = threadIdx.x;
  if (t < 40){
    int b = t/10, k = t - 10*(t/10);
    float a = b_fc[k];
    #pragma unroll 1
    for (int c=0;c<64;++c) a = fmaf(pooled[b*64+c]*(1.f/4096.f), w_fc[k*64+c], a);
    logits[b*10+k] = a;
  }
}

extern "C" void kernel_launch(void* const* d_in, const int* in_sizes, int n_in,
                              void* d_out, int out_size, void* d_ws, size_t ws_size,
                              hipStream_t stream)
{
  const float* x    = (const float*)d_in[0];
  const float* w_p  = (const float*)d_in[1];
  const float* b_p  = (const float*)d_in[2];
  const float* w_m  = (const float*)d_in[3];
  const float* b_m  = (const float*)d_in[4];
  const float* w_dc = (const float*)d_in[5];
  const float* g_d  = (const float*)d_in[6];
  const float* be_d = (const float*)d_in[7];
  const float* w_c1 = (const float*)d_in[8];
  const float* g1   = (const float*)d_in[9];
  const float* be1  = (const float*)d_in[10];
  const float* w_c2 = (const float*)d_in[11];
  const float* g2   = (const float*)d_in[12];
  const float* be2  = (const float*)d_in[13];
  const float* w_fc = (const float*)d_in[14];
  const float* b_fc = (const float*)d_in[15];

  float* out    = (float*)d_out;
  float* logits = out;                 // 40
  float* xxx    = out + 40;            // NV  (stage-2 raw y)
  float* p_out  = out + 40 + NV;       // NV*81

  // workspace layout
  float* ws     = (float*)d_ws;
  float* stats  = ws;                        // 512 floats
  float* pooled = stats + 512;               // 256
  short* wbf    = (short*)(pooled + 256);    // 27*64*32 bf16
  short* wo2    = wbf + 27*64*32;            // 112*32 bf16
  short* wc1b   = wo2 + 112*32;              // 32*32 bf16
  unsigned* xpair = (unsigned*)(wc1b + 32*32);       // 4*50^3 uint (bf16 pairs)
  float* y1     = (float*)(xpair + (size_t)BSZ*PS);  // NV fp32
  short* h1c    = (short*)(y1 + NV);         // (4*SS,32) bf16 channel-last
  short* t2c    = h1c + (size_t)NV*32;       // (4*SS,64) bf16 channel-last

  float* st_y1 = stats + 0;    // 2
  float* st_y2 = stats + 2;    // 2
  float* st_h1 = stats + 4;    // 64
  float* st_t2 = stats + 68;   // 128

  const int pblk = (BSZ*PS + 255)/256;

  // zero all stats + pooled (must happen every launch: atomics accumulate)
  hipMemsetAsync(stats, 0, (512+256)*sizeof(float), stream);

  // merged weight repack
  repack_kernel<<<(27*64*32 + 112*32 + 32*32 + 255)/256,256,0,stream>>>(
      w_c2, w_p, b_p, w_m, b_m, w_c1, wbf, wo2, wc1b);

  // ---- deform stage 1 (fused y-stats) ----
  pad_pair_kernel<<<pblk,256,0,stream>>>(x, xpair);
  deform3_kernel<false><<<1728,256,0,stream>>>(xpair, wo2, w_dc, y1, nullptr, st_y1);
  bnpad_pair_kernel<<<pblk,256,0,stream>>>(y1, st_y1, g_d, be_d, xpair);

  // ---- deform stage 2 (writes xxx and p; fused y-stats) ----
  deform3_kernel<true><<<1728,256,0,stream>>>(xpair, wo2, w_dc, xxx, p_out, st_y2);
  bnpad_pair_kernel<<<pblk,256,0,stream>>>(xxx, st_y2, g_d, be_d, xpair);

  // ---- conv1 via MFMA (fused h1 stats) ----
  conv1m_kernel<<<1728,256,0,stream>>>(xpair, wc1b, h1c, st_h1);

  // ---- conv2 via MFMA, inline BN+relu on h1, fused t2 stats; then pool ----
  conv2_mfma2<<<1728,256,0,stream>>>(h1c, wbf, st_h1, g1, be1, t2c, st_t2);
  pool64c_kernel<<<dim3(16,16,BSZ),128,0,stream>>>(t2c, st_t2, g2, be2, pooled);

  // ---- FC head ----
  fc_kernel<<<1,64,0,stream>>>(pooled, w_fc, b_fc, logits);
}

// Round 12
// 339.456 us; speedup vs baseline: 1.2614x; 1.2614x over previous
//
#include <hip/hip_runtime.h>
#include <math.h>

#define BSZ 4
#define DD 48
#define SS (48*48*48)          // 110592 spatial per (b, channel)
#define NV (BSZ*SS)            // 442368 voxels per channel over batch
#define PS 125000              // 50^3 padded volume
#define EPSBN 1e-5f

typedef __attribute__((ext_vector_type(8))) short bf16x8;
typedef __attribute__((ext_vector_type(4))) short s16x4;
typedef __attribute__((ext_vector_type(4))) float f32x4;

__device__ __forceinline__ short f2b(float f){           // fp32 -> bf16 bits (RNE)
  unsigned u = __float_as_uint(f);
  u = (u + 0x7FFFu + ((u>>16)&1u)) >> 16;
  return (short)u;
}
__device__ __forceinline__ float b2f(short s){
  return __uint_as_float(((unsigned)(unsigned short)s)<<16);
}

// ---------------- pad + pairify: x (4,48^3) fp32 -> pairh (4,50^3) uint -----
__global__ __launch_bounds__(256) void pad_pair_kernel(
    const float* __restrict__ src, unsigned* __restrict__ dst)
{
  int idx = blockIdx.x*256 + threadIdx.x;
  if (idx >= BSZ*PS) return;
  int b = idx / PS; int r = idx - b*PS;
  int z = r/2500; int r2 = r - z*2500; int yy = r2/50; int xx = r2 - yy*50;
  const float* sb = src + (size_t)b*SS;
  auto val = [&](int zz,int yv,int xv)->unsigned{
    float v = 0.f;
    if (zz>=1 && zz<=48 && yv>=1 && yv<=48 && xv>=1 && xv<=48)
      v = sb[(size_t)((zz-1)*48 + (yv-1))*48 + (xv-1)];
    return (unsigned)(unsigned short)f2b(v);
  };
  unsigned lo = val(z,yy,xx);
  unsigned hi = (xx<49) ? val(z,yy,xx+1) : 0u;
  dst[idx] = lo | (hi<<16);
}

// ---------------- fused BN+relu+pad+pairify: y -> pairh ---------------------
__global__ __launch_bounds__(256) void bnpad_pair_kernel(
    const float* __restrict__ y, const float* __restrict__ st,
    const float* __restrict__ gamma, const float* __restrict__ beta,
    unsigned* __restrict__ dst)
{
  int idx = blockIdx.x*256 + threadIdx.x;
  if (idx >= BSZ*PS) return;
  float mu  = st[0]*(1.f/(float)NV);
  float var = st[1]*(1.f/(float)NV) - mu*mu;
  float sc  = rsqrtf(var+EPSBN)*gamma[0];
  float sh  = beta[0] - mu*sc;
  int b = idx / PS; int r = idx - b*PS;
  int z = r/2500; int r2 = r - z*2500; int yy = r2/50; int xx = r2 - yy*50;
  const float* yb = y + (size_t)b*SS;
  auto val = [&](int zz,int yv,int xv)->unsigned{
    float v = 0.f;
    if (zz>=1 && zz<=48 && yv>=1 && yv<=48 && xv>=1 && xv<=48){
      float t = yb[(size_t)((zz-1)*48 + (yv-1))*48 + (xv-1)];
      v = fmaxf(fmaf(t, sc, sh), 0.f);
    }
    return (unsigned)(unsigned short)f2b(v);
  };
  unsigned lo = val(z,yy,xx);
  unsigned hi = (xx<49) ? val(z,yy,xx+1) : 0u;
  dst[idx] = lo | (hi<<16);
}

// ---------------- merged weight repack: wbf + wo2 + wc1b --------------------
__global__ void repack_kernel(
    const float* __restrict__ w_c2,
    const float* __restrict__ w_p, const float* __restrict__ b_p,
    const float* __restrict__ w_m, const float* __restrict__ b_m,
    const float* __restrict__ w_c1,
    short* __restrict__ wbf, short* __restrict__ wo2, short* __restrict__ wc1b)
{
  int o = blockIdx.x*256 + threadIdx.x;
  if (o < 27*64*32){
    int ci = o & 31; int co = (o>>5) & 63; int tap = o >> 11;
    wbf[o] = f2b(w_c2[(co*32+ci)*27 + tap]);
  } else if (o < 27*64*32 + 112*32){
    int o2 = o - 27*64*32;
    int k = o2 & 31; int c = o2 >> 5;
    int f = c >> 4, qq = (c >> 2) & 3, r = c & 3;
    int n = 4*f + qq;
    float v = 0.f;
    if (n < 27){
      if (k < 27)       v = (r < 3) ? w_p[(r*27+n)*27 + k] : w_m[n*27 + k];
      else if (k == 27) v = (r < 3) ? b_p[r*27+n]          : b_m[n];
    }
    wo2[o2] = f2b(v);
  } else if (o < 27*64*32 + 112*32 + 32*32){
    int o3 = o - 27*64*32 - 112*32;
    int k = o3 & 31; int c = o3 >> 5;
    wc1b[o3] = f2b(k < 27 ? w_c1[c*27 + k] : 0.f);
  }
}

// ---------------- deformable conv stage: pair-gather, barrier-free p dump ---
template<bool WRITE_P>
__global__ __launch_bounds__(256) void deform3_kernel(
    const unsigned* __restrict__ xpair,   // (4,50^3) bf16-pair table
    const short* __restrict__ wo2,        // [112][32] bf16
    const float* __restrict__ w_dc,
    float* __restrict__ y, float* __restrict__ p_out,
    float* __restrict__ st)               // [2] sum/sumsq of y (atomic)
{
  __shared__ short xt[6*6*18];                         // 2592 B halo (bf16)
  __shared__ __align__(16) float pbuf[WRITE_P ? 4*16*81 : 4];  // per-wave slices
  __shared__ float yred[8];

  int bid = blockIdx.x;
  int bw = bid % 3; int bh = (bid/3)%12; int bd = (bid/36)%12; int b = bid/432;
  int d0 = bd*4, h0 = bh*4, w0 = bw*16;
  int tid = threadIdx.x;
  const unsigned* xp = xpair + (size_t)b*PS;

  for (int e = tid; e < 648; e += 256){
    int z = e/108; int rem = e - z*108; int yy = rem/18; int xx = rem - yy*18;
    xt[e] = (short)(xp[(d0+z)*2500 + (h0+yy)*50 + (w0+xx)] & 0xffffu);
  }
  __syncthreads();

  int lane = tid & 63, wid = tid >> 6;
  int q = lane >> 4, n16 = lane & 15;

  bf16x8 aF[7];
  #pragma unroll
  for (int f=0; f<7; ++f)
    aF[f] = *(const bf16x8*)(wo2 + (f*16 + n16)*32 + q*8);

  int toffs[8];
  #pragma unroll
  for (int j=0;j<8;++j){
    int t = q*8 + j; int tc = t > 26 ? 0 : t;
    int kd = tc/9, rr = tc - kd*9, kh = rr/3, kw = rr - kh*3;
    toffs[j] = kd*108 + kh*18 + kw;
  }

  float wdcv[7], fkd[7], fkh[7], fkw[7];
  #pragma unroll
  for (int f=0; f<7; ++f){
    int n = 4*f + q;
    if (n < 27){
      int kd = n/9, rr = n - kd*9, kh = rr/3, kw = rr - kh*3;
      wdcv[f] = w_dc[n];
      fkd[f] = (float)kd; fkh[f] = (float)kh; fkw[f] = (float)kw;
    } else { wdcv[f]=0.f; fkd[f]=0.f; fkh[f]=0.f; fkw[f]=0.f; }
  }

  const short one_bf = (short)0x3F80;
  const f32x4 zero4 = {0.f,0.f,0.f,0.f};
  float based = (float)(d0 + wid);
  float basew = (float)(w0 + n16);
  float ys = 0.f, yq = 0.f;
  float* pw = pbuf + wid*1296;          // this wave's 16x81 slice

  #pragma unroll 1
  for (int dy=0; dy<4; ++dy){
    int vbase = wid*108 + dy*18 + n16;
    bf16x8 bF;
    #pragma unroll
    for (int j=0;j<8;++j){
      short xv = xt[vbase + toffs[j]];
      bF[j] = (j<3 || q<3) ? xv : one_bf;
    }
    f32x4 acc[7];
    #pragma unroll
    for (int f=0; f<7; ++f)
      acc[f] = __builtin_amdgcn_mfma_f32_16x16x32_bf16(aF[f], bF, zero4, 0,0,0);

    float baseh = (float)(h0 + dy);
    float accv = 0.f;
    #pragma unroll
    for (int f=0; f<7; ++f){
      int n = 4*f + q;
      if (n < 27){
        float od = acc[f][0], oh = acc[f][1], ow = acc[f][2], mr = acc[f][3];
        float mm = __builtin_amdgcn_rcpf(1.f + __expf(-mr));
        float pdv = based + fkd[f] + od;
        float phv = baseh + fkh[f] + oh;
        float pwv = basew + fkw[f] + ow;
        float fd0 = fminf(fmaxf(floorf(pdv),0.f),49.f), fd1 = fminf(fd0+1.f,49.f);
        float pdc = fminf(fmaxf(pdv,0.f),49.f);
        float wd0 = 1.f + fd0 - pdc, wd1 = 1.f - fd1 + pdc;
        float fh0 = fminf(fmaxf(floorf(phv),0.f),49.f), fh1 = fminf(fh0+1.f,49.f);
        float phc = fminf(fmaxf(phv,0.f),49.f);
        float wh0 = 1.f + fh0 - phc, wh1 = 1.f - fh1 + phc;
        float fw0 = fminf(fmaxf(floorf(pwv),0.f),49.f);
        float pwc = fminf(fmaxf(pwv,0.f),49.f);
        float fw1 = fminf(fw0+1.f,49.f);
        float wwa = 1.f + fw0 - pwc, wwb = 1.f - fw1 + pwc;
        int iz0 = (int)fd0*2500, iz1 = (int)fd1*2500;
        int iy0 = (int)fh0*50,   iy1 = (int)fh1*50;
        int ix0 = (int)fw0;
        bool sel = ix0 > 48;
        int ixp = sel ? 48 : ix0;
        unsigned p00 = xp[iz0+iy0+ixp], p01 = xp[iz0+iy1+ixp];
        unsigned p10 = xp[iz1+iy0+ixp], p11 = xp[iz1+iy1+ixp];
        float lo00=b2f((short)p00), hi00=b2f((short)(p00>>16));
        float lo01=b2f((short)p01), hi01=b2f((short)(p01>>16));
        float lo10=b2f((short)p10), hi10=b2f((short)(p10>>16));
        float lo11=b2f((short)p11), hi11=b2f((short)(p11>>16));
        float v000 = sel ? hi00 : lo00, v001 = hi00;
        float v010 = sel ? hi01 : lo01, v011 = hi01;
        float v100 = sel ? hi10 : lo10, v101 = hi10;
        float v110 = sel ? hi11 : lo11, v111 = hi11;
        float sv = wd0*(wh0*(wwa*v000+wwb*v001)+wh1*(wwa*v010+wwb*v011))
                 + wd1*(wh0*(wwa*v100+wwb*v101)+wh1*(wwa*v110+wwb*v111));
        accv += sv*mm*wdcv[f];
        if constexpr (WRITE_P){
          int vb = n16*81;
          pw[vb + n]      = pdc;
          pw[vb + 27 + n] = phc;
          pw[vb + 54 + n] = pwc;
        }
      }
    }
    accv += __shfl_xor(accv, 16);
    accv += __shfl_xor(accv, 32);
    if (q == 0){
      y[(size_t)b*SS + (size_t)((d0+wid)*48 + (h0+dy))*48 + (w0+n16)] = accv;
      ys += accv; yq += accv*accv;
    }

    if constexpr (WRITE_P){
      // per-wave dump: no barrier (intra-wave LDS RAW handled by waitcnt)
      size_t rbase = ((((size_t)b*48 + (d0+wid))*48 + (h0+dy))*48 + w0)*81;
      float* dst = p_out + rbase;
      #pragma unroll
      for (int k=0;k<6;++k){
        int i = lane + (k<<6);
        if (i < 324){
          f32x4 v = *(const f32x4*)(pw + i*4);
          *(f32x4*)(dst + i*4) = v;
        }
      }
    }
  }

  // fused y-stats: q==0 lanes (0..15) hold per-voxel partials
  ys += __shfl_xor(ys, 1); ys += __shfl_xor(ys, 2);
  ys += __shfl_xor(ys, 4); ys += __shfl_xor(ys, 8);
  yq += __shfl_xor(yq, 1); yq += __shfl_xor(yq, 2);
  yq += __shfl_xor(yq, 4); yq += __shfl_xor(yq, 8);
  if (lane == 0){ yred[wid] = ys; yred[4+wid] = yq; }
  __syncthreads();
  if (tid == 0) atomicAdd(&st[0], yred[0]+yred[1]+yred[2]+yred[3]);
  if (tid == 1) atomicAdd(&st[1], yred[4]+yred[5]+yred[6]+yred[7]);
}

// ---------------- conv1 via MFMA: 1 -> 32 channels, channel-last bf16 out ---
__global__ __launch_bounds__(256) void conv1m_kernel(
    const unsigned* __restrict__ xpair, const short* __restrict__ wc1b,
    short* __restrict__ h1c)
{
  __shared__ short xt[6*6*18];
  int bid = blockIdx.x;
  int bw = bid % 3; int bh = (bid/3)%12; int bd = (bid/36)%12; int b = bid/432;
  int d0 = bd*4, h0 = bh*4, w0 = bw*16;
  int tid = threadIdx.x;
  const unsigned* xp = xpair + (size_t)b*PS;

  for (int e = tid; e < 648; e += 256){
    int z = e/108; int rem = e - z*108; int yy = rem/18; int xx = rem - yy*18;
    xt[e] = (short)(xp[(d0+z)*2500 + (h0+yy)*50 + (w0+xx)] & 0xffffu);
  }
  __syncthreads();

  int lane = tid & 63, wid = tid >> 6;
  int q = lane >> 4, n16 = lane & 15;

  bf16x8 aF0 = *(const bf16x8*)(wc1b + n16*32 + q*8);
  bf16x8 aF1 = *(const bf16x8*)(wc1b + (16+n16)*32 + q*8);

  int toffs[8];
  #pragma unroll
  for (int j=0;j<8;++j){
    int t = q*8 + j; int tc = t > 26 ? 0 : t;
    int kd = tc/9, rr = tc - kd*9, kh = rr/3, kw = rr - kh*3;
    toffs[j] = kd*108 + kh*18 + kw;
  }

  const f32x4 zero4 = {0.f,0.f,0.f,0.f};
  #pragma unroll
  for (int dy=0; dy<4; ++dy){
    int vbase = wid*108 + dy*18 + n16;
    bf16x8 bF;
    #pragma unroll
    for (int j=0;j<8;++j) bF[j] = xt[vbase + toffs[j]];   // A k>=27 is 0
    f32x4 a0 = __builtin_amdgcn_mfma_f32_16x16x32_bf16(aF0, bF, zero4, 0,0,0);
    f32x4 a1 = __builtin_amdgcn_mfma_f32_16x16x32_bf16(aF1, bF, zero4, 0,0,0);
    size_t idx = (size_t)b*SS + (size_t)((d0+wid)*48 + (h0+dy))*48 + (w0+n16);
    s16x4 o0, o1;
    #pragma unroll
    for (int r=0;r<4;++r){ o0[r]=f2b(a0[r]); o1[r]=f2b(a1[r]); }
    *(s16x4*)(h1c + idx*32 + q*4)      = o0;
    *(s16x4*)(h1c + idx*32 + 16 + q*4) = o1;
  }
}

// ---------------- BN stats over channel-last bf16 (reg accumulators) --------
template<int NCH>
__global__ __launch_bounds__(256) void bn_stats_cl(
    const short* __restrict__ x, float* __restrict__ sums)
{
  constexpr int GPB = NCH/8;
  const long NG = (long)NV*GPB;
  int tid = threadIdx.x;
  f32x4 sa = {0.f,0.f,0.f,0.f}, sb = sa, qa = sa, qb = sa;
  for (long g = (long)blockIdx.x*256+tid; g < NG; g += (long)gridDim.x*256){
    bf16x8 v8 = *(const bf16x8*)(x + g*8);
    float v;
    v=b2f(v8[0]); sa[0]+=v; qa[0]+=v*v;
    v=b2f(v8[1]); sa[1]+=v; qa[1]+=v*v;
    v=b2f(v8[2]); sa[2]+=v; qa[2]+=v*v;
    v=b2f(v8[3]); sa[3]+=v; qa[3]+=v*v;
    v=b2f(v8[4]); sb[0]+=v; qb[0]+=v*v;
    v=b2f(v8[5]); sb[1]+=v; qb[1]+=v*v;
    v=b2f(v8[6]); sb[2]+=v; qb[2]+=v*v;
    v=b2f(v8[7]); sb[3]+=v; qb[3]+=v*v;
  }
  #pragma unroll
  for (int m = GPB; m < 64; m <<= 1){
    sa[0]+=__shfl_xor(sa[0],m); sa[1]+=__shfl_xor(sa[1],m);
    sa[2]+=__shfl_xor(sa[2],m); sa[3]+=__shfl_xor(sa[3],m);
    sb[0]+=__shfl_xor(sb[0],m); sb[1]+=__shfl_xor(sb[1],m);
    sb[2]+=__shfl_xor(sb[2],m); sb[3]+=__shfl_xor(sb[3],m);
    qa[0]+=__shfl_xor(qa[0],m); qa[1]+=__shfl_xor(qa[1],m);
    qa[2]+=__shfl_xor(qa[2],m); qa[3]+=__shfl_xor(qa[3],m);
    qb[0]+=__shfl_xor(qb[0],m); qb[1]+=__shfl_xor(qb[1],m);
    qb[2]+=__shfl_xor(qb[2],m); qb[3]+=__shfl_xor(qb[3],m);
  }
  int lane = tid & 63, wid = tid >> 6;
  __shared__ float red[4][GPB][16];
  if (lane < GPB){
    red[wid][lane][0]=sa[0];  red[wid][lane][1]=sa[1];
    red[wid][lane][2]=sa[2];  red[wid][lane][3]=sa[3];
    red[wid][lane][4]=sb[0];  red[wid][lane][5]=sb[1];
    red[wid][lane][6]=sb[2];  red[wid][lane][7]=sb[3];
    red[wid][lane][8]=qa[0];  red[wid][lane][9]=qa[1];
    red[wid][lane][10]=qa[2]; red[wid][lane][11]=qa[3];
    red[wid][lane][12]=qb[0]; red[wid][lane][13]=qb[1];
    red[wid][lane][14]=qb[2]; red[wid][lane][15]=qb[3];
  }
  __syncthreads();
  if (tid < GPB*16){
    int gi = tid >> 4, v = tid & 15;
    float t = red[0][gi][v] + red[1][gi][v] + red[2][gi][v] + red[3][gi][v];
    int ch = gi*8 + (v & 7);
    atomicAdd(&sums[2*ch + (v>>3)], t);
  }
}

// ---------------- conv2 via MFMA, inline BN+relu staging, weight prefetch ---
__global__ __launch_bounds__(256) void conv2_mfma2(
    const short* __restrict__ h1c, const short* __restrict__ wbf,
    const float* __restrict__ st1, const float* __restrict__ g1,
    const float* __restrict__ be1, short* __restrict__ t2c)
{
  __shared__ __align__(16) short slab[4*648*8];  // 41472 B
  __shared__ float ssc[32], ssh[32];
  int tid = threadIdx.x;
  if (tid < 32){
    float mu  = st1[2*tid]  *(1.f/(float)NV);
    float var = st1[2*tid+1]*(1.f/(float)NV) - mu*mu;
    float sc = rsqrtf(var+EPSBN)*g1[tid];
    ssc[tid]=sc; ssh[tid]=be1[tid]-mu*sc;
  }
  __syncthreads();

  int bid0 = blockIdx.x;
  int bid = (bid0 & 7)*216 + (bid0 >> 3);        // bijective XCD swizzle (1728=8*216)
  int bw = bid % 3; int bh = (bid/3)%12; int bd = (bid/36)%12; int b = bid/432;
  int d0 = bd*4, h0 = bh*4, w0 = bw*16;
  const short* hb = h1c + (size_t)b*SS*32;

  for (int e = tid; e < 648; e += 256){
    int z = e/108; int rem = e - z*108; int y = rem/18; int x = rem - y*18;
    int gd = d0-1+z, gh = h0-1+y, gw = w0-1+x;
    bool ok = ((unsigned)gd<48u)&&((unsigned)gh<48u)&&((unsigned)gw<48u);
    if (ok){
      const bf16x8* src = (const bf16x8*)(hb + (size_t)((gd*48+gh)*48+gw)*32);
      #pragma unroll
      for (int g8=0; g8<4; ++g8){
        bf16x8 raw = src[g8];
        bf16x8 outv;
        #pragma unroll
        for (int j=0;j<8;++j){
          float v = fmaxf(fmaf(b2f(raw[j]), ssc[g8*8+j], ssh[g8*8+j]), 0.f);
          outv[j] = f2b(v);
        }
        *(bf16x8*)&slab[(g8*648+e)*8] = outv;
      }
    } else {
      bf16x8 zz = {0,0,0,0,0,0,0,0};
      #pragma unroll
      for (int g8=0; g8<4; ++g8) *(bf16x8*)&slab[(g8*648+e)*8] = zz;
    }
  }
  __syncthreads();

  int lane = tid & 63, wid = tid >> 6;
  int q = lane >> 4, n16 = lane & 15;
  f32x4 zero4 = {0.f,0.f,0.f,0.f};
  f32x4 acc[4][4];
  #pragma unroll
  for (int i=0;i<4;++i)
  #pragma unroll
  for (int j=0;j<4;++j) acc[i][j] = zero4;

  const short* wlane = wbf + n16*32 + q*8;
  bf16x8 aF[4], aFn[4];
  #pragma unroll
  for (int mb=0; mb<4; ++mb)
    aF[mb] = *(const bf16x8*)(wlane + mb*16*32);

  #pragma unroll 1
  for (int tap=0; tap<27; ++tap){
    // prefetch next tap's weights while this tap's MFMAs run
    if (tap < 26){
      const short* wn = wlane + (size_t)(tap+1)*64*32;
      #pragma unroll
      for (int mb=0; mb<4; ++mb)
        aFn[mb] = *(const bf16x8*)(wn + mb*16*32);
    }
    int kd = tap/9; int kh = (tap/3)%3; int kw = tap%3;
    int zz = wid + kd;
    #pragma unroll
    for (int dy=0; dy<4; ++dy){
      int e = (zz*6 + (dy+kh))*18 + (n16+kw);
      bf16x8 bF = *(const bf16x8*)&slab[(q*648 + e)*8];
      #pragma unroll
      for (int mb=0; mb<4; ++mb)
        acc[mb][dy] = __builtin_amdgcn_mfma_f32_16x16x32_bf16(aF[mb], bF, acc[mb][dy], 0,0,0);
    }
    #pragma unroll
    for (int mb=0; mb<4; ++mb) aF[mb] = aFn[mb];
  }

  short* tb = t2c + (size_t)b*SS*64;
  #pragma unroll
  for (int dy=0; dy<4; ++dy){
    int svox = ((d0+wid)*48 + (h0+dy))*48 + (w0+n16);
    #pragma unroll
    for (int mb=0; mb<4; ++mb){
      s16x4 o4;
      #pragma unroll
      for (int r=0;r<4;++r) o4[r] = f2b(acc[mb][dy][r]);
      *(s16x4*)(tb + (size_t)svox*64 + mb*16 + q*4) = o4;
    }
  }
}

// ---------------- BN + relu + maxpool + spatial-sum, channel-last -----------
__global__ __launch_bounds__(128) void pool64c_kernel(
    const short* __restrict__ t2c, const float* __restrict__ sums,
    const float* __restrict__ gamma, const float* __restrict__ beta,
    float* __restrict__ pooled)
{
  __shared__ float ssc[64], ssh[64];
  int tid = threadIdx.x;
  if (tid < 64){
    float mu  = sums[2*tid]  *(1.f/(float)NV);
    float var = sums[2*tid+1]*(1.f/(float)NV) - mu*mu;
    float sc = rsqrtf(var+EPSBN)*gamma[tid];
    ssc[tid]=sc; ssh[tid]=beta[tid]-mu*sc;
  }
  __syncthreads();
  int b = blockIdx.z, pd = blockIdx.y, ph = blockIdx.x;
  int c8 = tid & 7, pw = tid >> 3;
  const short* tb = t2c + (size_t)b*SS*64;
  f32x4 mxa = {-1e30f,-1e30f,-1e30f,-1e30f}, mxb = mxa;
  float sc0=ssc[c8*8+0], sc1=ssc[c8*8+1], sc2=ssc[c8*8+2], sc3=ssc[c8*8+3];
  float sc4=ssc[c8*8+4], sc5=ssc[c8*8+5], sc6=ssc[c8*8+6], sc7=ssc[c8*8+7];
  float sh0=ssh[c8*8+0], sh1=ssh[c8*8+1], sh2=ssh[c8*8+2], sh3=ssh[c8*8+3];
  float sh4=ssh[c8*8+4], sh5=ssh[c8*8+5], sh6=ssh[c8*8+6], sh7=ssh[c8*8+7];
  #pragma unroll
  for (int kd=0;kd<3;++kd)
  #pragma unroll 1
  for (int kh=0;kh<3;++kh)
  #pragma unroll
  for (int kw=0;kw<3;++kw){
    int vox = ((pd*3+kd)*48 + (ph*3+kh))*48 + (pw*3+kw);
    bf16x8 v8 = *(const bf16x8*)(tb + (size_t)vox*64 + c8*8);
    float v;
    v = fmaxf(fmaf(b2f(v8[0]), sc0, sh0), 0.f); mxa[0] = fmaxf(mxa[0], v);
    v = fmaxf(fmaf(b2f(v8[1]), sc1, sh1), 0.f); mxa[1] = fmaxf(mxa[1], v);
    v = fmaxf(fmaf(b2f(v8[2]), sc2, sh2), 0.f); mxa[2] = fmaxf(mxa[2], v);
    v = fmaxf(fmaf(b2f(v8[3]), sc3, sh3), 0.f); mxa[3] = fmaxf(mxa[3], v);
    v = fmaxf(fmaf(b2f(v8[4]), sc4, sh4), 0.f); mxb[0] = fmaxf(mxb[0], v);
    v = fmaxf(fmaf(b2f(v8[5]), sc5, sh5), 0.f); mxb[1] = fmaxf(mxb[1], v);
    v = fmaxf(fmaf(b2f(v8[6]), sc6, sh6), 0.f); mxb[2] = fmaxf(mxb[2], v);
    v = fmaxf(fmaf(b2f(v8[7]), sc7, sh7), 0.f); mxb[3] = fmaxf(mxb[3], v);
  }
  __shared__ float r[128][8];
  r[tid][0]=mxa[0]; r[tid][1]=mxa[1]; r[tid][2]=mxa[2]; r[tid][3]=mxa[3];
  r[tid][4]=mxb[0]; r[tid][5]=mxb[1]; r[tid][6]=mxb[2]; r[tid][7]=mxb[3];
  __syncthreads();
  for (int o=64;o>=8;o>>=1){
    if (tid<o){
      #pragma unroll
      for (int j=0;j<8;++j) r[tid][j]+=r[tid+o][j];
    }
    __syncthreads();
  }
  if (tid<8){
    #pragma unroll
    for (int j=0;j<8;++j) atomicAdd(&pooled[b*64 + tid*8 + j], r[tid][j]);
  }
}

// ---------------- FC head ----------------
__global__ void fc_kernel(const float* __restrict__ pooled,
                          const float* __restrict__ w_fc, const float* __restrict__ b_fc,
                          float* __restrict__ logits)
{
  int t = threadIdx.x;
  if (t < 40){
    int b = t/10, k = t - 10*(t/10);
    float a = b_fc[k];
    #pragma unroll 1
    for (int c=0;c<64;++c) a = fmaf(pooled[b*64+c]*(1.f/4096.f), w_fc[k*64+c], a);
    logits[b*10+k] = a;
  }
}

extern "C" void kernel_launch(void* const* d_in, const int* in_sizes, int n_in,
                              void* d_out, int out_size, void* d_ws, size_t ws_size,
                              hipStream_t stream)
{
  const float* x    = (const float*)d_in[0];
  const float* w_p  = (const float*)d_in[1];
  const float* b_p  = (const float*)d_in[2];
  const float* w_m  = (const float*)d_in[3];
  const float* b_m  = (const float*)d_in[4];
  const float* w_dc = (const float*)d_in[5];
  const float* g_d  = (const float*)d_in[6];
  const float* be_d = (const float*)d_in[7];
  const float* w_c1 = (const float*)d_in[8];
  const float* g1   = (const float*)d_in[9];
  const float* be1  = (const float*)d_in[10];
  const float* w_c2 = (const float*)d_in[11];
  const float* g2   = (const float*)d_in[12];
  const float* be2  = (const float*)d_in[13];
  const float* w_fc = (const float*)d_in[14];
  const float* b_fc = (const float*)d_in[15];

  float* out    = (float*)d_out;
  float* logits = out;                 // 40
  float* xxx    = out + 40;            // NV  (stage-2 raw y)
  float* p_out  = out + 40 + NV;       // NV*81

  // workspace layout
  float* ws     = (float*)d_ws;
  float* stats  = ws;                        // 512 floats
  float* pooled = stats + 512;               // 256
  short* wbf    = (short*)(pooled + 256);    // 27*64*32 bf16
  short* wo2    = wbf + 27*64*32;            // 112*32 bf16
  short* wc1b   = wo2 + 112*32;              // 32*32 bf16
  unsigned* xpair = (unsigned*)(wc1b + 32*32);       // 4*50^3 uint (bf16 pairs)
  float* y1     = (float*)(xpair + (size_t)BSZ*PS);  // NV fp32
  short* h1c    = (short*)(y1 + NV);         // (4*SS,32) bf16 channel-last
  short* t2c    = h1c + (size_t)NV*32;       // (4*SS,64) bf16 channel-last

  float* st_y1 = stats + 0;    // 2
  float* st_y2 = stats + 2;    // 2
  float* st_h1 = stats + 4;    // 64
  float* st_t2 = stats + 68;   // 128

  const int pblk = (BSZ*PS + 255)/256;

  // zero all stats + pooled (must happen every launch: atomics accumulate)
  hipMemsetAsync(stats, 0, (512+256)*sizeof(float), stream);

  // merged weight repack
  repack_kernel<<<(27*64*32 + 112*32 + 32*32 + 255)/256,256,0,stream>>>(
      w_c2, w_p, b_p, w_m, b_m, w_c1, wbf, wo2, wc1b);

  // ---- deform stage 1 (fused y-stats) ----
  pad_pair_kernel<<<pblk,256,0,stream>>>(x, xpair);
  deform3_kernel<false><<<1728,256,0,stream>>>(xpair, wo2, w_dc, y1, nullptr, st_y1);
  bnpad_pair_kernel<<<pblk,256,0,stream>>>(y1, st_y1, g_d, be_d, xpair);

  // ---- deform stage 2 (writes xxx and p; fused y-stats) ----
  deform3_kernel<true><<<1728,256,0,stream>>>(xpair, wo2, w_dc, xxx, p_out, st_y2);
  bnpad_pair_kernel<<<pblk,256,0,stream>>>(xxx, st_y2, g_d, be_d, xpair);

  // ---- conv1 via MFMA ----
  conv1m_kernel<<<1728,256,0,stream>>>(xpair, wc1b, h1c);
  bn_stats_cl<32><<<256,256,0,stream>>>(h1c, st_h1);

  // ---- conv2 via MFMA, inline BN+relu on h1; then t2 stats + pool ----
  conv2_mfma2<<<1728,256,0,stream>>>(h1c, wbf, st_h1, g1, be1, t2c);
  bn_stats_cl<64><<<512,256,0,stream>>>(t2c, st_t2);
  pool64c_kernel<<<dim3(16,16,BSZ),128,0,stream>>>(t2c, st_t2, g2, be2, pooled);

  // ---- FC head ----
  fc_kernel<<<1,64,0,stream>>>(pooled, w_fc, b_fc, logits);
}

// Round 13
// 330.135 us; speedup vs baseline: 1.2970x; 1.0282x over previous
//
#include <hip/hip_runtime.h>
#include <math.h>

#define BSZ 4
#define DD 48
#define SS (48*48*48)          // 110592 spatial per (b, channel)
#define NV (BSZ*SS)            // 442368 voxels per channel over batch
#define PS 125000              // 50^3 padded volume
#define EPSBN 1e-5f

typedef __attribute__((ext_vector_type(8))) short bf16x8;
typedef __attribute__((ext_vector_type(4))) short s16x4;
typedef __attribute__((ext_vector_type(4))) float f32x4;

__device__ __forceinline__ short f2b(float f){           // fp32 -> bf16 bits (RNE)
  unsigned u = __float_as_uint(f);
  u = (u + 0x7FFFu + ((u>>16)&1u)) >> 16;
  return (short)u;
}
__device__ __forceinline__ float b2f(short s){
  return __uint_as_float(((unsigned)(unsigned short)s)<<16);
}

// ---------------- pad + pairify: x (4,48^3) fp32 -> pairh (4,50^3) uint -----
__global__ __launch_bounds__(256) void pad_pair_kernel(
    const float* __restrict__ src, unsigned* __restrict__ dst)
{
  int idx = blockIdx.x*256 + threadIdx.x;
  if (idx >= BSZ*PS) return;
  int b = idx / PS; int r = idx - b*PS;
  int z = r/2500; int r2 = r - z*2500; int yy = r2/50; int xx = r2 - yy*50;
  const float* sb = src + (size_t)b*SS;
  auto val = [&](int zz,int yv,int xv)->unsigned{
    float v = 0.f;
    if (zz>=1 && zz<=48 && yv>=1 && yv<=48 && xv>=1 && xv<=48)
      v = sb[(size_t)((zz-1)*48 + (yv-1))*48 + (xv-1)];
    return (unsigned)(unsigned short)f2b(v);
  };
  unsigned lo = val(z,yy,xx);
  unsigned hi = (xx<49) ? val(z,yy,xx+1) : 0u;
  dst[idx] = lo | (hi<<16);
}

// ---------------- fused BN+relu+pad+pairify: y -> pairh ---------------------
__global__ __launch_bounds__(256) void bnpad_pair_kernel(
    const float* __restrict__ y, const float* __restrict__ st,
    const float* __restrict__ gamma, const float* __restrict__ beta,
    unsigned* __restrict__ dst)
{
  int idx = blockIdx.x*256 + threadIdx.x;
  if (idx >= BSZ*PS) return;
  float mu  = st[0]*(1.f/(float)NV);
  float var = st[1]*(1.f/(float)NV) - mu*mu;
  float sc  = rsqrtf(var+EPSBN)*gamma[0];
  float sh  = beta[0] - mu*sc;
  int b = idx / PS; int r = idx - b*PS;
  int z = r/2500; int r2 = r - z*2500; int yy = r2/50; int xx = r2 - yy*50;
  const float* yb = y + (size_t)b*SS;
  auto val = [&](int zz,int yv,int xv)->unsigned{
    float v = 0.f;
    if (zz>=1 && zz<=48 && yv>=1 && yv<=48 && xv>=1 && xv<=48){
      float t = yb[(size_t)((zz-1)*48 + (yv-1))*48 + (xv-1)];
      v = fmaxf(fmaf(t, sc, sh), 0.f);
    }
    return (unsigned)(unsigned short)f2b(v);
  };
  unsigned lo = val(z,yy,xx);
  unsigned hi = (xx<49) ? val(z,yy,xx+1) : 0u;
  dst[idx] = lo | (hi<<16);
}

// ---------------- merged weight repack: wbf + wo2 + wc1b --------------------
__global__ void repack_kernel(
    const float* __restrict__ w_c2,
    const float* __restrict__ w_p, const float* __restrict__ b_p,
    const float* __restrict__ w_m, const float* __restrict__ b_m,
    const float* __restrict__ w_c1,
    short* __restrict__ wbf, short* __restrict__ wo2, short* __restrict__ wc1b)
{
  int o = blockIdx.x*256 + threadIdx.x;
  if (o < 27*64*32){
    int ci = o & 31; int co = (o>>5) & 63; int tap = o >> 11;
    wbf[o] = f2b(w_c2[(co*32+ci)*27 + tap]);
  } else if (o < 27*64*32 + 112*32){
    int o2 = o - 27*64*32;
    int k = o2 & 31; int c = o2 >> 5;
    int f = c >> 4, qq = (c >> 2) & 3, r = c & 3;
    int n = 4*f + qq;
    float v = 0.f;
    if (n < 27){
      if (k < 27)       v = (r < 3) ? w_p[(r*27+n)*27 + k] : w_m[n*27 + k];
      else if (k == 27) v = (r < 3) ? b_p[r*27+n]          : b_m[n];
    }
    wo2[o2] = f2b(v);
  } else if (o < 27*64*32 + 112*32 + 32*32){
    int o3 = o - 27*64*32 - 112*32;
    int k = o3 & 31; int c = o3 >> 5;
    wc1b[o3] = f2b(k < 27 ? w_c1[c*27 + k] : 0.f);
  }
}

// ---------------- deformable conv stage: pair-gather, barrier-free p dump ---
template<bool WRITE_P>
__global__ __launch_bounds__(256) void deform3_kernel(
    const unsigned* __restrict__ xpair,   // (4,50^3) bf16-pair table
    const short* __restrict__ wo2,        // [112][32] bf16
    const float* __restrict__ w_dc,
    float* __restrict__ y, float* __restrict__ p_out,
    float* __restrict__ st)               // [2] sum/sumsq of y (atomic)
{
  __shared__ short xt[6*6*18];                         // 2592 B halo (bf16)
  __shared__ __align__(16) float pbuf[WRITE_P ? 4*16*81 : 4];  // per-wave slices
  __shared__ float yred[8];

  int bid0 = blockIdx.x;
  int bid = (bid0 & 7)*216 + (bid0 >> 3);   // bijective XCD swizzle (1728=8*216)
  int bw = bid % 3; int bh = (bid/3)%12; int bd = (bid/36)%12; int b = bid/432;
  int d0 = bd*4, h0 = bh*4, w0 = bw*16;
  int tid = threadIdx.x;
  const unsigned* xp = xpair + (size_t)b*PS;

  for (int e = tid; e < 648; e += 256){
    int z = e/108; int rem = e - z*108; int yy = rem/18; int xx = rem - yy*18;
    xt[e] = (short)(xp[(d0+z)*2500 + (h0+yy)*50 + (w0+xx)] & 0xffffu);
  }
  __syncthreads();

  int lane = tid & 63, wid = tid >> 6;
  int q = lane >> 4, n16 = lane & 15;

  bf16x8 aF[7];
  #pragma unroll
  for (int f=0; f<7; ++f)
    aF[f] = *(const bf16x8*)(wo2 + (f*16 + n16)*32 + q*8);

  int toffs[8];
  #pragma unroll
  for (int j=0;j<8;++j){
    int t = q*8 + j; int tc = t > 26 ? 0 : t;
    int kd = tc/9, rr = tc - kd*9, kh = rr/3, kw = rr - kh*3;
    toffs[j] = kd*108 + kh*18 + kw;
  }

  float wdcv[7], fkd[7], fkh[7], fkw[7];
  #pragma unroll
  for (int f=0; f<7; ++f){
    int n = 4*f + q;
    if (n < 27){
      int kd = n/9, rr = n - kd*9, kh = rr/3, kw = rr - kh*3;
      wdcv[f] = w_dc[n];
      fkd[f] = (float)kd; fkh[f] = (float)kh; fkw[f] = (float)kw;
    } else { wdcv[f]=0.f; fkd[f]=0.f; fkh[f]=0.f; fkw[f]=0.f; }
  }

  const short one_bf = (short)0x3F80;
  const f32x4 zero4 = {0.f,0.f,0.f,0.f};
  float based = (float)(d0 + wid);
  float basew = (float)(w0 + n16);
  float ys = 0.f, yq = 0.f;
  float* pw = pbuf + wid*1296;          // this wave's 16x81 slice

  #pragma unroll 1
  for (int dy=0; dy<4; ++dy){
    int vbase = wid*108 + dy*18 + n16;
    bf16x8 bF;
    #pragma unroll
    for (int j=0;j<8;++j){
      short xv = xt[vbase + toffs[j]];
      bF[j] = (j<3 || q<3) ? xv : one_bf;
    }
    f32x4 acc[7];
    #pragma unroll
    for (int f=0; f<7; ++f)
      acc[f] = __builtin_amdgcn_mfma_f32_16x16x32_bf16(aF[f], bF, zero4, 0,0,0);

    float baseh = (float)(h0 + dy);
    float accv = 0.f;
    #pragma unroll
    for (int f=0; f<7; ++f){
      int n = 4*f + q;
      if (n < 27){
        float od = acc[f][0], oh = acc[f][1], ow = acc[f][2], mr = acc[f][3];
        float mm = __builtin_amdgcn_rcpf(1.f + __expf(-mr));
        float pdv = based + fkd[f] + od;
        float phv = baseh + fkh[f] + oh;
        float pwv = basew + fkw[f] + ow;
        float fd0 = fminf(fmaxf(floorf(pdv),0.f),49.f), fd1 = fminf(fd0+1.f,49.f);
        float pdc = fminf(fmaxf(pdv,0.f),49.f);
        float wd0 = 1.f + fd0 - pdc, wd1 = 1.f - fd1 + pdc;
        float fh0 = fminf(fmaxf(floorf(phv),0.f),49.f), fh1 = fminf(fh0+1.f,49.f);
        float phc = fminf(fmaxf(phv,0.f),49.f);
        float wh0 = 1.f + fh0 - phc, wh1 = 1.f - fh1 + phc;
        float fw0 = fminf(fmaxf(floorf(pwv),0.f),49.f);
        float pwc = fminf(fmaxf(pwv,0.f),49.f);
        float fw1 = fminf(fw0+1.f,49.f);
        float wwa = 1.f + fw0 - pwc, wwb = 1.f - fw1 + pwc;
        int iz0 = (int)fd0*2500, iz1 = (int)fd1*2500;
        int iy0 = (int)fh0*50,   iy1 = (int)fh1*50;
        int ix0 = (int)fw0;
        bool sel = ix0 > 48;
        int ixp = sel ? 48 : ix0;
        unsigned p00 = xp[iz0+iy0+ixp], p01 = xp[iz0+iy1+ixp];
        unsigned p10 = xp[iz1+iy0+ixp], p11 = xp[iz1+iy1+ixp];
        float lo00=b2f((short)p00), hi00=b2f((short)(p00>>16));
        float lo01=b2f((short)p01), hi01=b2f((short)(p01>>16));
        float lo10=b2f((short)p10), hi10=b2f((short)(p10>>16));
        float lo11=b2f((short)p11), hi11=b2f((short)(p11>>16));
        float v000 = sel ? hi00 : lo00, v001 = hi00;
        float v010 = sel ? hi01 : lo01, v011 = hi01;
        float v100 = sel ? hi10 : lo10, v101 = hi10;
        float v110 = sel ? hi11 : lo11, v111 = hi11;
        float sv = wd0*(wh0*(wwa*v000+wwb*v001)+wh1*(wwa*v010+wwb*v011))
                 + wd1*(wh0*(wwa*v100+wwb*v101)+wh1*(wwa*v110+wwb*v111));
        accv += sv*mm*wdcv[f];
        if constexpr (WRITE_P){
          int vb = n16*81;
          pw[vb + n]      = pdc;
          pw[vb + 27 + n] = phc;
          pw[vb + 54 + n] = pwc;
        }
      }
    }
    accv += __shfl_xor(accv, 16);
    accv += __shfl_xor(accv, 32);
    if (q == 0){
      y[(size_t)b*SS + (size_t)((d0+wid)*48 + (h0+dy))*48 + (w0+n16)] = accv;
      ys += accv; yq += accv*accv;
    }

    if constexpr (WRITE_P){
      // per-wave dump, non-temporal (p never re-read on device -> keep L2 for gathers)
      size_t rbase = ((((size_t)b*48 + (d0+wid))*48 + (h0+dy))*48 + w0)*81;
      float* dst = p_out + rbase;
      #pragma unroll
      for (int k=0;k<6;++k){
        int i = lane + (k<<6);
        if (i < 324){
          f32x4 v = *(const f32x4*)(pw + i*4);
          __builtin_nontemporal_store(v, (f32x4*)(dst + i*4));
        }
      }
    }
  }

  // fused y-stats: q==0 lanes (0..15) hold per-voxel partials
  ys += __shfl_xor(ys, 1); ys += __shfl_xor(ys, 2);
  ys += __shfl_xor(ys, 4); ys += __shfl_xor(ys, 8);
  yq += __shfl_xor(yq, 1); yq += __shfl_xor(yq, 2);
  yq += __shfl_xor(yq, 4); yq += __shfl_xor(yq, 8);
  if (lane == 0){ yred[wid] = ys; yred[4+wid] = yq; }
  __syncthreads();
  if (tid == 0) atomicAdd(&st[0], yred[0]+yred[1]+yred[2]+yred[3]);
  if (tid == 1) atomicAdd(&st[1], yred[4]+yred[5]+yred[6]+yred[7]);
}

// ---------------- conv1 via MFMA: 1 -> 32 channels, channel-last bf16 out ---
__global__ __launch_bounds__(256) void conv1m_kernel(
    const unsigned* __restrict__ xpair, const short* __restrict__ wc1b,
    short* __restrict__ h1c)
{
  __shared__ short xt[6*6*18];
  int bid0 = blockIdx.x;
  int bid = (bid0 & 7)*216 + (bid0 >> 3);   // bijective XCD swizzle
  int bw = bid % 3; int bh = (bid/3)%12; int bd = (bid/36)%12; int b = bid/432;
  int d0 = bd*4, h0 = bh*4, w0 = bw*16;
  int tid = threadIdx.x;
  const unsigned* xp = xpair + (size_t)b*PS;

  for (int e = tid; e < 648; e += 256){
    int z = e/108; int rem = e - z*108; int yy = rem/18; int xx = rem - yy*18;
    xt[e] = (short)(xp[(d0+z)*2500 + (h0+yy)*50 + (w0+xx)] & 0xffffu);
  }
  __syncthreads();

  int lane = tid & 63, wid = tid >> 6;
  int q = lane >> 4, n16 = lane & 15;

  bf16x8 aF0 = *(const bf16x8*)(wc1b + n16*32 + q*8);
  bf16x8 aF1 = *(const bf16x8*)(wc1b + (16+n16)*32 + q*8);

  int toffs[8];
  #pragma unroll
  for (int j=0;j<8;++j){
    int t = q*8 + j; int tc = t > 26 ? 0 : t;
    int kd = tc/9, rr = tc - kd*9, kh = rr/3, kw = rr - kh*3;
    toffs[j] = kd*108 + kh*18 + kw;
  }

  const f32x4 zero4 = {0.f,0.f,0.f,0.f};
  #pragma unroll
  for (int dy=0; dy<4; ++dy){
    int vbase = wid*108 + dy*18 + n16;
    bf16x8 bF;
    #pragma unroll
    for (int j=0;j<8;++j) bF[j] = xt[vbase + toffs[j]];   // A k>=27 is 0
    f32x4 a0 = __builtin_amdgcn_mfma_f32_16x16x32_bf16(aF0, bF, zero4, 0,0,0);
    f32x4 a1 = __builtin_amdgcn_mfma_f32_16x16x32_bf16(aF1, bF, zero4, 0,0,0);
    size_t idx = (size_t)b*SS + (size_t)((d0+wid)*48 + (h0+dy))*48 + (w0+n16);
    s16x4 o0, o1;
    #pragma unroll
    for (int r=0;r<4;++r){ o0[r]=f2b(a0[r]); o1[r]=f2b(a1[r]); }
    *(s16x4*)(h1c + idx*32 + q*4)      = o0;
    *(s16x4*)(h1c + idx*32 + 16 + q*4) = o1;
  }
}

// ---------------- BN stats over channel-last bf16 (reg accumulators) --------
template<int NCH>
__global__ __launch_bounds__(256) void bn_stats_cl(
    const short* __restrict__ x, float* __restrict__ sums)
{
  constexpr int GPB = NCH/8;
  const long NG = (long)NV*GPB;
  int tid = threadIdx.x;
  f32x4 sa = {0.f,0.f,0.f,0.f}, sb = sa, qa = sa, qb = sa;
  for (long g = (long)blockIdx.x*256+tid; g < NG; g += (long)gridDim.x*256){
    bf16x8 v8 = *(const bf16x8*)(x + g*8);
    float v;
    v=b2f(v8[0]); sa[0]+=v; qa[0]+=v*v;
    v=b2f(v8[1]); sa[1]+=v; qa[1]+=v*v;
    v=b2f(v8[2]); sa[2]+=v; qa[2]+=v*v;
    v=b2f(v8[3]); sa[3]+=v; qa[3]+=v*v;
    v=b2f(v8[4]); sb[0]+=v; qb[0]+=v*v;
    v=b2f(v8[5]); sb[1]+=v; qb[1]+=v*v;
    v=b2f(v8[6]); sb[2]+=v; qb[2]+=v*v;
    v=b2f(v8[7]); sb[3]+=v; qb[3]+=v*v;
  }
  #pragma unroll
  for (int m = GPB; m < 64; m <<= 1){
    sa[0]+=__shfl_xor(sa[0],m); sa[1]+=__shfl_xor(sa[1],m);
    sa[2]+=__shfl_xor(sa[2],m); sa[3]+=__shfl_xor(sa[3],m);
    sb[0]+=__shfl_xor(sb[0],m); sb[1]+=__shfl_xor(sb[1],m);
    sb[2]+=__shfl_xor(sb[2],m); sb[3]+=__shfl_xor(sb[3],m);
    qa[0]+=__shfl_xor(qa[0],m); qa[1]+=__shfl_xor(qa[1],m);
    qa[2]+=__shfl_xor(qa[2],m); qa[3]+=__shfl_xor(qa[3],m);
    qb[0]+=__shfl_xor(qb[0],m); qb[1]+=__shfl_xor(qb[1],m);
    qb[2]+=__shfl_xor(qb[2],m); qb[3]+=__shfl_xor(qb[3],m);
  }
  int lane = tid & 63, wid = tid >> 6;
  __shared__ float red[4][GPB][16];
  if (lane < GPB){
    red[wid][lane][0]=sa[0];  red[wid][lane][1]=sa[1];
    red[wid][lane][2]=sa[2];  red[wid][lane][3]=sa[3];
    red[wid][lane][4]=sb[0];  red[wid][lane][5]=sb[1];
    red[wid][lane][6]=sb[2];  red[wid][lane][7]=sb[3];
    red[wid][lane][8]=qa[0];  red[wid][lane][9]=qa[1];
    red[wid][lane][10]=qa[2]; red[wid][lane][11]=qa[3];
    red[wid][lane][12]=qb[0]; red[wid][lane][13]=qb[1];
    red[wid][lane][14]=qb[2]; red[wid][lane][15]=qb[3];
  }
  __syncthreads();
  if (tid < GPB*16){
    int gi = tid >> 4, v = tid & 15;
    float t = red[0][gi][v] + red[1][gi][v] + red[2][gi][v] + red[3][gi][v];
    int ch = gi*8 + (v & 7);
    atomicAdd(&sums[2*ch + (v>>3)], t);
  }
}

// ---------------- conv2 via MFMA, inline BN+relu staging --------------------
__global__ __launch_bounds__(256) void conv2_mfma2(
    const short* __restrict__ h1c, const short* __restrict__ wbf,
    const float* __restrict__ st1, const float* __restrict__ g1,
    const float* __restrict__ be1, short* __restrict__ t2c)
{
  __shared__ __align__(16) short slab[4*648*8];  // 41472 B
  __shared__ float ssc[32], ssh[32];
  int tid = threadIdx.x;
  if (tid < 32){
    float mu  = st1[2*tid]  *(1.f/(float)NV);
    float var = st1[2*tid+1]*(1.f/(float)NV) - mu*mu;
    float sc = rsqrtf(var+EPSBN)*g1[tid];
    ssc[tid]=sc; ssh[tid]=be1[tid]-mu*sc;
  }
  __syncthreads();

  int bid0 = blockIdx.x;
  int bid = (bid0 & 7)*216 + (bid0 >> 3);        // bijective XCD swizzle (1728=8*216)
  int bw = bid % 3; int bh = (bid/3)%12; int bd = (bid/36)%12; int b = bid/432;
  int d0 = bd*4, h0 = bh*4, w0 = bw*16;
  const short* hb = h1c + (size_t)b*SS*32;

  for (int e = tid; e < 648; e += 256){
    int z = e/108; int rem = e - z*108; int y = rem/18; int x = rem - y*18;
    int gd = d0-1+z, gh = h0-1+y, gw = w0-1+x;
    bool ok = ((unsigned)gd<48u)&&((unsigned)gh<48u)&&((unsigned)gw<48u);
    if (ok){
      const bf16x8* src = (const bf16x8*)(hb + (size_t)((gd*48+gh)*48+gw)*32);
      #pragma unroll
      for (int g8=0; g8<4; ++g8){
        bf16x8 raw = src[g8];
        bf16x8 outv;
        #pragma unroll
        for (int j=0;j<8;++j){
          float v = fmaxf(fmaf(b2f(raw[j]), ssc[g8*8+j], ssh[g8*8+j]), 0.f);
          outv[j] = f2b(v);
        }
        *(bf16x8*)&slab[(g8*648+e)*8] = outv;
      }
    } else {
      bf16x8 zz = {0,0,0,0,0,0,0,0};
      #pragma unroll
      for (int g8=0; g8<4; ++g8) *(bf16x8*)&slab[(g8*648+e)*8] = zz;
    }
  }
  __syncthreads();

  int lane = tid & 63, wid = tid >> 6;
  int q = lane >> 4, n16 = lane & 15;
  f32x4 zero4 = {0.f,0.f,0.f,0.f};
  f32x4 acc[4][4];
  #pragma unroll
  for (int i=0;i<4;++i)
  #pragma unroll
  for (int j=0;j<4;++j) acc[i][j] = zero4;

  #pragma unroll 1
  for (int tap=0; tap<27; ++tap){
    int kd = tap/9; int kh = (tap/3)%3; int kw = tap%3;
    const short* wp = wbf + (size_t)tap*64*32 + n16*32 + q*8;
    bf16x8 aF[4];
    #pragma unroll
    for (int mb=0; mb<4; ++mb)
      aF[mb] = *(const bf16x8*)(wp + mb*16*32);

    int zz = wid + kd;
    #pragma unroll
    for (int dy=0; dy<4; ++dy){
      int e = (zz*6 + (dy+kh))*18 + (n16+kw);
      bf16x8 bF = *(const bf16x8*)&slab[(q*648 + e)*8];
      #pragma unroll
      for (int mb=0; mb<4; ++mb)
        acc[mb][dy] = __builtin_amdgcn_mfma_f32_16x16x32_bf16(aF[mb], bF, acc[mb][dy], 0,0,0);
    }
  }

  short* tb = t2c + (size_t)b*SS*64;
  #pragma unroll
  for (int dy=0; dy<4; ++dy){
    int svox = ((d0+wid)*48 + (h0+dy))*48 + (w0+n16);
    #pragma unroll
    for (int mb=0; mb<4; ++mb){
      s16x4 o4;
      #pragma unroll
      for (int r=0;r<4;++r) o4[r] = f2b(acc[mb][dy][r]);
      *(s16x4*)(tb + (size_t)svox*64 + mb*16 + q*4) = o4;
    }
  }
}

// ---------------- BN + relu + maxpool + spatial-sum, channel-last -----------
__global__ __launch_bounds__(128) void pool64c_kernel(
    const short* __restrict__ t2c, const float* __restrict__ sums,
    const float* __restrict__ gamma, const float* __restrict__ beta,
    float* __restrict__ pooled)
{
  __shared__ float ssc[64], ssh[64];
  int tid = threadIdx.x;
  if (tid < 64){
    float mu  = sums[2*tid]  *(1.f/(float)NV);
    float var = sums[2*tid+1]*(1.f/(float)NV) - mu*mu;
    float sc = rsqrtf(var+EPSBN)*gamma[tid];
    ssc[tid]=sc; ssh[tid]=beta[tid]-mu*sc;
  }
  __syncthreads();
  int b = blockIdx.z, pd = blockIdx.y, ph = blockIdx.x;
  int c8 = tid & 7, pw = tid >> 3;
  const short* tb = t2c + (size_t)b*SS*64;
  f32x4 mxa = {-1e30f,-1e30f,-1e30f,-1e30f}, mxb = mxa;
  float sc0=ssc[c8*8+0], sc1=ssc[c8*8+1], sc2=ssc[c8*8+2], sc3=ssc[c8*8+3];
  float sc4=ssc[c8*8+4], sc5=ssc[c8*8+5], sc6=ssc[c8*8+6], sc7=ssc[c8*8+7];
  float sh0=ssh[c8*8+0], sh1=ssh[c8*8+1], sh2=ssh[c8*8+2], sh3=ssh[c8*8+3];
  float sh4=ssh[c8*8+4], sh5=ssh[c8*8+5], sh6=ssh[c8*8+6], sh7=ssh[c8*8+7];
  #pragma unroll
  for (int kd=0;kd<3;++kd)
  #pragma unroll 1
  for (int kh=0;kh<3;++kh)
  #pragma unroll
  for (int kw=0;kw<3;++kw){
    int vox = ((pd*3+kd)*48 + (ph*3+kh))*48 + (pw*3+kw);
    bf16x8 v8 = *(const bf16x8*)(tb + (size_t)vox*64 + c8*8);
    float v;
    v = fmaxf(fmaf(b2f(v8[0]), sc0, sh0), 0.f); mxa[0] = fmaxf(mxa[0], v);
    v = fmaxf(fmaf(b2f(v8[1]), sc1, sh1), 0.f); mxa[1] = fmaxf(mxa[1], v);
    v = fmaxf(fmaf(b2f(v8[2]), sc2, sh2), 0.f); mxa[2] = fmaxf(mxa[2], v);
    v = fmaxf(fmaf(b2f(v8[3]), sc3, sh3), 0.f); mxa[3] = fmaxf(mxa[3], v);
    v = fmaxf(fmaf(b2f(v8[4]), sc4, sh4), 0.f); mxb[0] = fmaxf(mxb[0], v);
    v = fmaxf(fmaf(b2f(v8[5]), sc5, sh5), 0.f); mxb[1] = fmaxf(mxb[1], v);
    v = fmaxf(fmaf(b2f(v8[6]), sc6, sh6), 0.f); mxb[2] = fmaxf(mxb[2], v);
    v = fmaxf(fmaf(b2f(v8[7]), sc7, sh7), 0.f); mxb[3] = fmaxf(mxb[3], v);
  }
  __shared__ float r[128][8];
  r[tid][0]=mxa[0]; r[tid][1]=mxa[1]; r[tid][2]=mxa[2]; r[tid][3]=mxa[3];
  r[tid][4]=mxb[0]; r[tid][5]=mxb[1]; r[tid][6]=mxb[2]; r[tid][7]=mxb[3];
  __syncthreads();
  for (int o=64;o>=8;o>>=1){
    if (tid<o){
      #pragma unroll
      for (int j=0;j<8;++j) r[tid][j]+=r[tid+o][j];
    }
    __syncthreads();
  }
  if (tid<8){
    #pragma unroll
    for (int j=0;j<8;++j) atomicAdd(&pooled[b*64 + tid*8 + j], r[tid][j]);
  }
}

// ---------------- FC head ----------------
__global__ void fc_kernel(const float* __restrict__ pooled,
                          const float* __restrict__ w_fc, const float* __restrict__ b_fc,
                          float* __restrict__ logits)
{
  int t = threadIdx.x;
  if (t < 40){
    int b = t/10, k = t - 10*(t/10);
    float a = b_fc[k];
    #pragma unroll 1
    for (int c=0;c<64;++c) a = fmaf(pooled[b*64+c]*(1.f/4096.f), w_fc[k*64+c], a);
    logits[b*10+k] = a;
  }
}

extern "C" void kernel_launch(void* const* d_in, const int* in_sizes, int n_in,
                              void* d_out, int out_size, void* d_ws, size_t ws_size,
                              hipStream_t stream)
{
  const float* x    = (const float*)d_in[0];
  const float* w_p  = (const float*)d_in[1];
  const float* b_p  = (const float*)d_in[2];
  const float* w_m  = (const float*)d_in[3];
  const float* b_m  = (const float*)d_in[4];
  const float* w_dc = (const float*)d_in[5];
  const float* g_d  = (const float*)d_in[6];
  const float* be_d = (const float*)d_in[7];
  const float* w_c1 = (const float*)d_in[8];
  const float* g1   = (const float*)d_in[9];
  const float* be1  = (const float*)d_in[10];
  const float* w_c2 = (const float*)d_in[11];
  const float* g2   = (const float*)d_in[12];
  const float* be2  = (const float*)d_in[13];
  const float* w_fc = (const float*)d_in[14];
  const float* b_fc = (const float*)d_in[15];

  float* out    = (float*)d_out;
  float* logits = out;                 // 40
  float* xxx    = out + 40;            // NV  (stage-2 raw y)
  float* p_out  = out + 40 + NV;       // NV*81

  // workspace layout
  float* ws     = (float*)d_ws;
  float* stats  = ws;                        // 512 floats
  float* pooled = stats + 512;               // 256
  short* wbf    = (short*)(pooled + 256);    // 27*64*32 bf16
  short* wo2    = wbf + 27*64*32;            // 112*32 bf16
  short* wc1b   = wo2 + 112*32;              // 32*32 bf16
  unsigned* xpair = (unsigned*)(wc1b + 32*32);       // 4*50^3 uint (bf16 pairs)
  float* y1     = (float*)(xpair + (size_t)BSZ*PS);  // NV fp32
  short* h1c    = (short*)(y1 + NV);         // (4*SS,32) bf16 channel-last
  short* t2c    = h1c + (size_t)NV*32;       // (4*SS,64) bf16 channel-last

  float* st_y1 = stats + 0;    // 2
  float* st_y2 = stats + 2;    // 2
  float* st_h1 = stats + 4;    // 64
  float* st_t2 = stats + 68;   // 128

  const int pblk = (BSZ*PS + 255)/256;

  // zero all stats + pooled (must happen every launch: atomics accumulate)
  hipMemsetAsync(stats, 0, (512+256)*sizeof(float), stream);

  // merged weight repack
  repack_kernel<<<(27*64*32 + 112*32 + 32*32 + 255)/256,256,0,stream>>>(
      w_c2, w_p, b_p, w_m, b_m, w_c1, wbf, wo2, wc1b);

  // ---- deform stage 1 (fused y-stats) ----
  pad_pair_kernel<<<pblk,256,0,stream>>>(x, xpair);
  deform3_kernel<false><<<1728,256,0,stream>>>(xpair, wo2, w_dc, y1, nullptr, st_y1);
  bnpad_pair_kernel<<<pblk,256,0,stream>>>(y1, st_y1, g_d, be_d, xpair);

  // ---- deform stage 2 (writes xxx and p; fused y-stats) ----
  deform3_kernel<true><<<1728,256,0,stream>>>(xpair, wo2, w_dc, xxx, p_out, st_y2);
  bnpad_pair_kernel<<<pblk,256,0,stream>>>(xxx, st_y2, g_d, be_d, xpair);

  // ---- conv1 via MFMA ----
  conv1m_kernel<<<1728,256,0,stream>>>(xpair, wc1b, h1c);
  bn_stats_cl<32><<<256,256,0,stream>>>(h1c, st_h1);

  // ---- conv2 via MFMA, inline BN+relu on h1; then t2 stats + pool ----
  conv2_mfma2<<<1728,256,0,stream>>>(h1c, wbf, st_h1, g1, be1, t2c);
  bn_stats_cl<64><<<512,256,0,stream>>>(t2c, st_t2);
  pool64c_kernel<<<dim3(16,16,BSZ),128,0,stream>>>(t2c, st_t2, g2, be2, pooled);

  // ---- FC head ----
  fc_kernel<<<1,64,0,stream>>>(pooled, w_fc, b_fc, logits);
}